// Round 10
// baseline (772.378 us; speedup 1.0000x reference)
//
#include <hip/hip_runtime.h>
#include <hip/hip_cooperative_groups.h>
namespace cg = cooperative_groups;

#define NUM_GRAPHS 1024
#define BIN_BITS 10
#define BIN_SIZE (1 << BIN_BITS)      // 1024 nodes per bin
#define CURS 16                       // cursor stride in ints (64 B)
// standalone scatter (fallback path)
#define EB 4096
#define STH 512
#define EPT 8
#define SWAVES 8
// accum / fused kernel
#define ACCTH 256                     // 4 waves
#define ACCW 4
#define FEPT 8                        // edges/thread/chunk in fused scatter
#define FCHK (ACCTH * FEPT)           // 2048 edges per chunk

typedef int v4i __attribute__((ext_vector_type(4)));  // native vec for nt-load

__device__ inline unsigned bf16_rn(float f) {
    unsigned u = __float_as_uint(f);
    return (u + 0x7FFFu + ((u >> 16) & 1u)) >> 16;
}

// ---- shared accum machinery (r5/r7's measured-best v7: f32 planes,
//      10-ballot match + rank-ordered multipass RMW; zero atomics) ----
#define LOADR(B, PE, VM) do {                                              \
    int _i = (B) + lane * 4;                                               \
    if (_i + 3 < s1) {                                                     \
        v4i _p4 = __builtin_nontemporal_load((const v4i*)(packed + _i));   \
        PE[0] = _p4.x; PE[1] = _p4.y; PE[2] = _p4.z; PE[3] = _p4.w;        \
        VM = 0xF;                                                          \
    } else {                                                               \
        VM = 0;                                                            \
        PE[0] = (_i + 0 < s1) ? (VM |= 1, packed[_i + 0]) : 0;             \
        PE[1] = (_i + 1 < s1) ? (VM |= 2, packed[_i + 1]) : 0;             \
        PE[2] = (_i + 2 < s1) ? (VM |= 4, packed[_i + 2]) : 0;             \
        PE[3] = (_i + 3 < s1) ? (VM |= 8, packed[_i + 3]) : 0;             \
    }                                                                      \
} while (0)

#define GATHR(PE, G) do {                                                  \
    G[0] = x16[PE[0] & 0x7FFFF];                                           \
    G[1] = x16[PE[1] & 0x7FFFF];                                           \
    G[2] = x16[PE[2] & 0x7FFFF];                                           \
    G[3] = x16[PE[3] & 0x7FFFF];                                           \
} while (0)

#define PROCR(PE, G, VM) do {                                              \
    _Pragma("unroll")                                                      \
    for (int k = 0; k < 4; ++k) {                                          \
        int p = PE[k];                                                     \
        int dl = (((unsigned)p) >> 19) & (BIN_SIZE - 1);                   \
        unsigned long long m = ~0ull;                                      \
        _Pragma("unroll")                                                  \
        for (int bb = 0; bb < BIN_BITS; ++bb) {                            \
            unsigned long long bm = __ballot((dl >> bb) & 1);              \
            m &= ((dl >> bb) & 1) ? bm : ~bm;                              \
        }                                                                  \
        int rank = (int)__popcll(m & ((1ull << lane) - 1ull));             \
        float sc = ((VM >> k) & 1) ? 1.0f : 0.0f;                          \
        float v0 = __uint_as_float(G[k].x << 16) * sc;                     \
        float v1 = __uint_as_float(G[k].x & 0xFFFF0000u) * sc;             \
        float v2 = __uint_as_float(G[k].y << 16) * sc;                     \
        float v3 = __uint_as_float(G[k].y & 0xFFFF0000u) * sc;             \
        float4* pp = (float4*)&planes[wave][dl][0];                        \
        for (int pass = 0; __any(rank >= pass); ++pass) {                  \
            if (rank == pass) {                                            \
                float4 a = *pp;                                            \
                a.x += v0; a.y += v1; a.z += v2; a.w += v3;                \
                *pp = a;                                                   \
            }                                                              \
        }                                                                  \
    }                                                                      \
} while (0)

// ---------------------------------------------------------------------------
// FUSED cooperative kernel: init+prep | scatter | accum+MLP+pool | softmax,
// separated by grid.sync(). Removes ~4 inter-dispatch gaps (~28 us each,
// r4 bookkeeping). Scatter = proven ballot-rank (zero per-edge atomics),
// chunked 2048 edges, grid-stride. Accum = v7 verbatim (measured best,
// ~155 us). packed visibility across XCDs: __threadfence + grid.sync
// (device-scope release/acquire). gsum read back via atomic-fetch (+0.0),
// the pattern r9 validated for cross-block f32 sums.
// LDS: planes 64 KB; scatter's hist/wbase (16 KB) overlaid on planes.
// ---------------------------------------------------------------------------
__global__ void __launch_bounds__(ACCTH) fused_gin(
        const float4* __restrict__ x, uint2* __restrict__ x16,
        const int* __restrict__ src, const int* __restrict__ dst,
        int* __restrict__ packed, int* __restrict__ cursor,
        const int* __restrict__ batch, const float* __restrict__ eps_p,
        const float* __restrict__ W1, const float* __restrict__ b1,
        const float* __restrict__ W2, const float* __restrict__ b2,
        float* __restrict__ gsum, float* __restrict__ gcnt,
        float* __restrict__ out,
        int N, int E, int cap, int nb) {
    cg::grid_group grid = cg::this_grid();
    __shared__ float planes[ACCW][BIN_SIZE][4];       // 64 KB
    int* hist  = (int*)&planes[0][0][0];              // [4][512] overlay
    int* wbase = hist + ACCW * 512;                   // [4][512] overlay

    const int t = threadIdx.x;
    const int lane = t & 63;
    const int wave = t >> 6;
    const int nblk = gridDim.x;
    const int gid0 = blockIdx.x * ACCTH + t;
    const int gstr = nblk * ACCTH;

    // ---- phase 0: init cursors/gsum/gcnt + x -> bf16x4 table (L2-res) ----
    for (int i = gid0; i < 512; i += gstr) cursor[i * CURS] = 0;
    for (int i = gid0; i < NUM_GRAPHS * 4; i += gstr) gsum[i] = 0.0f;
    for (int i = gid0; i < NUM_GRAPHS; i += gstr) gcnt[i] = 0.0f;
    for (int i = gid0; i < N; i += gstr) {
        float4 v = x[i];
        uint2 r;
        r.x = bf16_rn(v.x) | (bf16_rn(v.y) << 16);
        r.y = bf16_rn(v.z) | (bf16_rn(v.w) << 16);
        x16[i] = r;
    }
    grid.sync();

    // ---- phase A: scatter (zero per-edge atomics; plain stores via L2) ----
    const int nchunks = (E + FCHK - 1) / FCHK;
    for (int ch = blockIdx.x; ch < nchunks; ch += nblk) {
        const int b0 = ch * FCHK;
        const int myBase = b0 + t * FEPT;

        for (int j = t; j < ACCW * 512; j += ACCTH) hist[j] = 0;
        __syncthreads();

        int dbuf[FEPT], sbuf[FEPT];
        const bool full = (myBase + FEPT <= E);
        if (full) {
            *(int4*)(dbuf)     = *(const int4*)(dst + myBase);
            *(int4*)(dbuf + 4) = *(const int4*)(dst + myBase + 4);
            *(int4*)(sbuf)     = *(const int4*)(src + myBase);
            *(int4*)(sbuf + 4) = *(const int4*)(src + myBase + 4);
        } else {
#pragma unroll
            for (int i = 0; i < FEPT; ++i) {
                int e = myBase + i;
                bool ok = e < E;
                dbuf[i] = ok ? dst[e] : 0;
                sbuf[i] = ok ? src[e] : 0;
            }
        }

        int pv[FEPT], bnlp[FEPT];
#pragma unroll
        for (int k = 0; k < FEPT; ++k) {
            int e = myBase + k;
            bool ok = full || (e < E);
            int d = dbuf[k];
            int bn = ((unsigned)d) >> BIN_BITS;            // < 512
            pv[k] = ((d & (BIN_SIZE - 1)) << 19) | sbuf[k];
            unsigned long long m = __ballot(ok);
#pragma unroll
            for (int bb = 0; bb < 9; ++bb) {
                unsigned long long bm = __ballot((bn >> bb) & 1);
                m &= ((bn >> bb) & 1) ? bm : ~bm;
            }
            int rank = (int)__popcll(m & ((1ull << lane) - 1ull));
            int cnt  = (int)__popcll(m);
            int leader = __ffsll((unsigned long long)m) - 1;
            int old = hist[wave * 512 + bn];               // group: same addr
            if (ok && lane == leader) hist[wave * 512 + bn] = old + cnt;
            bnlp[k] = ok ? ((bn << 16) | (old + rank)) : -1;
        }
        __syncthreads();

        for (int j = t; j < 512; j += ACCTH) {
            int c0 = hist[0 * 512 + j], c1 = hist[1 * 512 + j];
            int c2 = hist[2 * 512 + j], c3 = hist[3 * 512 + j];
            int total = c0 + c1 + c2 + c3;
            int base = j * cap;                 // relative cursors
            if (j < nb && total > 0) base += atomicAdd(&cursor[j * CURS], total);
            wbase[0 * 512 + j] = base;
            wbase[1 * 512 + j] = base + c0;
            wbase[2 * 512 + j] = base + c0 + c1;
            wbase[3 * 512 + j] = base + c0 + c1 + c2;
        }
        __syncthreads();

        if (full) {
#pragma unroll
            for (int k = 0; k < FEPT; ++k) {
                int bn = ((unsigned)bnlp[k]) >> 16;
                int lp = bnlp[k] & 0xFFFF;
                int pos = wbase[wave * 512 + bn] + lp;
                if (pos < (bn + 1) * cap)          // overflow guard
                    packed[pos] = pv[k];           // plain store (r4 lesson)
            }
        } else {
#pragma unroll
            for (int k = 0; k < FEPT; ++k) {
                if (bnlp[k] >= 0) {
                    int bn = ((unsigned)bnlp[k]) >> 16;
                    int lp = bnlp[k] & 0xFFFF;
                    int pos = wbase[wave * 512 + bn] + lp;
                    if (pos < (bn + 1) * cap)
                        packed[pos] = pv[k];
                }
            }
        }
        __syncthreads();   // wbase reads done before next chunk's hist zero
    }
    __threadfence();
    grid.sync();

    // ---- phase B: accum (v7) + MLP + pool, bin-stride ----
    for (int bin = blockIdx.x; bin < nb; bin += nblk) {
        {
            float4 z; z.x = 0.f; z.y = 0.f; z.z = 0.f; z.w = 0.f;
            float4* pz = (float4*)&planes[0][0][0];
#pragma unroll
            for (int i = 0; i < 16; ++i) pz[t + i * ACCTH] = z;
        }
        __syncthreads();

        const int startb = bin * cap;
        int cnt = cursor[bin * CURS];
        if (cnt > cap) cnt = cap;
        if (cnt < 0) cnt = 0;
        const int endb = startb + cnt;
        int seg = ((cnt + ACCW - 1) / ACCW + 3) & ~3;
        int s0 = startb + wave * seg;
        int s1 = s0 + seg; if (s1 > endb) s1 = endb;

        for (int b = s0; b < s1; b += 256) {
            int pe[4]; int vm; uint2 g[4];
            LOADR(b, pe, vm);
            GATHR(pe, g);
            PROCR(pe, g, vm);
        }
        __syncthreads();

        const float eps = eps_p[0];
        for (int hb = 0; hb < 4; ++hb) {
            int node = t + hb * ACCTH;             // 0..1023
            float4 a = *(const float4*)&planes[0][node][0];
#pragma unroll
            for (int w = 1; w < ACCW; ++w) {
                float4 bq = *(const float4*)&planes[w][node][0];
                a.x += bq.x; a.y += bq.y; a.z += bq.z; a.w += bq.w;
            }

            int n = bin * BIN_SIZE + node;
            bool valid = n < N;
            float o0 = 0.f, o1 = 0.f, o2 = 0.f, o3 = 0.f;
            int g = -1;
            if (valid) {
                float4 xv = x[n];
                float h0 = (1.0f + eps) * xv.x + a.x;
                float h1 = (1.0f + eps) * xv.y + a.y;
                float h2 = (1.0f + eps) * xv.z + a.z;
                float h3 = (1.0f + eps) * xv.w + a.w;

                float tmp[16];
#pragma unroll
                for (int j = 0; j < 16; ++j) {
                    float v = b1[j] + h0 * W1[j] + h1 * W1[16 + j] + h2 * W1[32 + j] + h3 * W1[48 + j];
                    tmp[j] = v > 0.0f ? v : 0.0f;
                }
                float o[4];
#pragma unroll
                for (int j = 0; j < 4; ++j) {
                    float v = b2[j];
#pragma unroll
                    for (int k = 0; k < 16; ++k) v += tmp[k] * W2[k * 4 + j];
                    o[j] = v > 0.0f ? v : 0.0f;
                }
                o0 = o[0]; o1 = o[1]; o2 = o[2]; o3 = o[3];
                g = batch[n];
            }

            int g0 = __shfl(g, 0);
            bool uni = __all(g == g0);
            if (uni && g0 >= 0) {
#pragma unroll
                for (int off = 32; off > 0; off >>= 1) {
                    o0 += __shfl_down(o0, off);
                    o1 += __shfl_down(o1, off);
                    o2 += __shfl_down(o2, off);
                    o3 += __shfl_down(o3, off);
                }
                if (lane == 0) {
                    unsafeAtomicAdd(&gsum[(size_t)g0 * 4 + 0], o0);
                    unsafeAtomicAdd(&gsum[(size_t)g0 * 4 + 1], o1);
                    unsafeAtomicAdd(&gsum[(size_t)g0 * 4 + 2], o2);
                    unsafeAtomicAdd(&gsum[(size_t)g0 * 4 + 3], o3);
                    unsafeAtomicAdd(&gcnt[g0], 64.0f);
                }
            } else if (valid) {
                unsafeAtomicAdd(&gsum[(size_t)g * 4 + 0], o0);
                unsafeAtomicAdd(&gsum[(size_t)g * 4 + 1], o1);
                unsafeAtomicAdd(&gsum[(size_t)g * 4 + 2], o2);
                unsafeAtomicAdd(&gsum[(size_t)g * 4 + 3], o3);
                unsafeAtomicAdd(&gcnt[g], 1.0f);
            }
        }
        __syncthreads();   // protect planes before next bin
    }
    __threadfence();
    grid.sync();

    // ---- phase C: log_softmax (atomic-fetch reads: XCD-safe, r9 pattern) --
    for (int g = gid0; g < NUM_GRAPHS; g += gstr) {
        float c = fmaxf(unsafeAtomicAdd(&gcnt[g], 0.0f), 1.0f);
        float p0 = unsafeAtomicAdd(&gsum[g * 4 + 0], 0.0f) / c;
        float p1 = unsafeAtomicAdd(&gsum[g * 4 + 1], 0.0f) / c;
        float p2 = unsafeAtomicAdd(&gsum[g * 4 + 2], 0.0f) / c;
        float p3 = unsafeAtomicAdd(&gsum[g * 4 + 3], 0.0f) / c;
        float m = fmaxf(fmaxf(p0, p1), fmaxf(p2, p3));
        float s = expf(p0 - m) + expf(p1 - m) + expf(p2 - m) + expf(p3 - m);
        float lse = m + logf(s);
        out[g * 4 + 0] = p0 - lse;
        out[g * 4 + 1] = p1 - lse;
        out[g * 4 + 2] = p2 - lse;
        out[g * 4 + 3] = p3 - lse;
    }
}

// ---------------------------------------------------------------------------
// Non-cooperative fallback pipeline (r8-proven): scatter v9 + accum v7 +
// softmax. Used when cooperative launch is unavailable.
// ---------------------------------------------------------------------------
__global__ void __launch_bounds__(STH, 6) bin_scatter(const float4* __restrict__ x,
                                                      uint2* __restrict__ x16,
                                                      const int* __restrict__ src,
                                                      const int* __restrict__ dst,
                                                      int* __restrict__ packed,
                                                      int* __restrict__ cursor,
                                                      int N, int E, int cap, int nb) {
    __shared__ int hist[SWAVES][512];
    __shared__ int wbase[SWAVES][512];

    const int t = threadIdx.x;
    const int lane = t & 63;
    const int wave = t >> 6;
    const int b0 = blockIdx.x * EB;
    const int myBase = b0 + t * EPT;

    {
        int nd = blockIdx.x * STH + t;
        if (nd < N) {
            float4 v = x[nd];
            uint2 r;
            r.x = bf16_rn(v.x) | (bf16_rn(v.y) << 16);
            r.y = bf16_rn(v.z) | (bf16_rn(v.w) << 16);
            x16[nd] = r;
        }
    }

    for (int j = t; j < SWAVES * 512; j += STH) (&hist[0][0])[j] = 0;
    __syncthreads();

    int dbuf[EPT], sbuf[EPT];
    const bool full = (myBase + EPT <= E);
    if (full) {
        *(int4*)(dbuf)     = *(const int4*)(dst + myBase);
        *(int4*)(dbuf + 4) = *(const int4*)(dst + myBase + 4);
        *(int4*)(sbuf)     = *(const int4*)(src + myBase);
        *(int4*)(sbuf + 4) = *(const int4*)(src + myBase + 4);
    } else {
#pragma unroll
        for (int i = 0; i < EPT; ++i) {
            int e = myBase + i;
            bool ok = e < E;
            dbuf[i] = ok ? dst[e] : 0;
            sbuf[i] = ok ? src[e] : 0;
        }
    }

    int pv[EPT];
    int bnlp[EPT];
#pragma unroll
    for (int k = 0; k < EPT; ++k) {
        int e = myBase + k;
        bool ok = full || (e < E);
        int d = dbuf[k];
        int bn = ((unsigned)d) >> BIN_BITS;
        pv[k] = ((d & (BIN_SIZE - 1)) << 19) | sbuf[k];
        unsigned long long m = __ballot(ok);
#pragma unroll
        for (int bb = 0; bb < 9; ++bb) {
            unsigned long long bm = __ballot((bn >> bb) & 1);
            m &= ((bn >> bb) & 1) ? bm : ~bm;
        }
        int rank = (int)__popcll(m & ((1ull << lane) - 1ull));
        int cnt  = (int)__popcll(m);
        int leader = __ffsll((unsigned long long)m) - 1;
        int old = hist[wave][bn];
        if (ok && lane == leader) hist[wave][bn] = old + cnt;
        bnlp[k] = ok ? ((bn << 16) | (old + rank)) : -1;
    }
    __syncthreads();

    {
        int c[SWAVES];
        int total = 0;
#pragma unroll
        for (int w = 0; w < SWAVES; ++w) { c[w] = hist[w][t]; total += c[w]; }
        int base = t * cap;
        if (t < nb && total > 0) base += atomicAdd(&cursor[t * CURS], total);
        int acc = base;
#pragma unroll
        for (int w = 0; w < SWAVES; ++w) { wbase[w][t] = acc; acc += c[w]; }
    }
    __syncthreads();

    if (full) {
#pragma unroll
        for (int k = 0; k < EPT; ++k) {
            int bn = ((unsigned)bnlp[k]) >> 16;
            int lp = bnlp[k] & 0xFFFF;
            int pos = wbase[wave][bn] + lp;
            if (pos < (bn + 1) * cap)
                packed[pos] = pv[k];
        }
    } else {
#pragma unroll
        for (int k = 0; k < EPT; ++k) {
            if (bnlp[k] >= 0) {
                int bn = ((unsigned)bnlp[k]) >> 16;
                int lp = bnlp[k] & 0xFFFF;
                int pos = wbase[wave][bn] + lp;
                if (pos < (bn + 1) * cap)
                    packed[pos] = pv[k];
            }
        }
    }
}

__global__ void __launch_bounds__(ACCTH) bin_accum_mlp_pool(
        const float4* __restrict__ x,
        const uint2* __restrict__ x16,
        const int* __restrict__ packed,
        const int* __restrict__ cursor,
        const int* __restrict__ batch,
        const float* __restrict__ eps_p,
        const float* __restrict__ W1, const float* __restrict__ b1,
        const float* __restrict__ W2, const float* __restrict__ b2,
        float* __restrict__ gsum, float* __restrict__ gcnt,
        int N, int cap) {
    __shared__ float planes[ACCW][BIN_SIZE][4];

    const int bin = blockIdx.x;
    const int t = threadIdx.x;
    const int lane = t & 63;
    const int wave = t >> 6;

    {
        float4 z; z.x = 0.f; z.y = 0.f; z.z = 0.f; z.w = 0.f;
        float4* pz = (float4*)&planes[0][0][0];
#pragma unroll
        for (int i = 0; i < 16; ++i) pz[t + i * ACCTH] = z;
    }
    __syncthreads();

    const int startb = bin * cap;
    int cnt = cursor[bin * CURS];
    if (cnt > cap) cnt = cap;
    if (cnt < 0) cnt = 0;
    const int endb = startb + cnt;
    int seg = ((cnt + ACCW - 1) / ACCW + 3) & ~3;
    int s0 = startb + wave * seg;
    int s1 = s0 + seg; if (s1 > endb) s1 = endb;

    for (int b = s0; b < s1; b += 256) {
        int pe[4]; int vm; uint2 g[4];
        LOADR(b, pe, vm);
        GATHR(pe, g);
        PROCR(pe, g, vm);
    }
    __syncthreads();

    const float eps = eps_p[0];
    for (int hb = 0; hb < 4; ++hb) {
        int node = t + hb * ACCTH;
        float4 a = *(const float4*)&planes[0][node][0];
#pragma unroll
        for (int w = 1; w < ACCW; ++w) {
            float4 bq = *(const float4*)&planes[w][node][0];
            a.x += bq.x; a.y += bq.y; a.z += bq.z; a.w += bq.w;
        }

        int n = bin * BIN_SIZE + node;
        bool valid = n < N;
        float o0 = 0.f, o1 = 0.f, o2 = 0.f, o3 = 0.f;
        int g = -1;
        if (valid) {
            float4 xv = x[n];
            float h0 = (1.0f + eps) * xv.x + a.x;
            float h1 = (1.0f + eps) * xv.y + a.y;
            float h2 = (1.0f + eps) * xv.z + a.z;
            float h3 = (1.0f + eps) * xv.w + a.w;

            float tmp[16];
#pragma unroll
            for (int j = 0; j < 16; ++j) {
                float v = b1[j] + h0 * W1[j] + h1 * W1[16 + j] + h2 * W1[32 + j] + h3 * W1[48 + j];
                tmp[j] = v > 0.0f ? v : 0.0f;
            }
            float o[4];
#pragma unroll
            for (int j = 0; j < 4; ++j) {
                float v = b2[j];
#pragma unroll
                for (int k = 0; k < 16; ++k) v += tmp[k] * W2[k * 4 + j];
                o[j] = v > 0.0f ? v : 0.0f;
            }
            o0 = o[0]; o1 = o[1]; o2 = o[2]; o3 = o[3];
            g = batch[n];
        }

        int g0 = __shfl(g, 0);
        bool uni = __all(g == g0);
        if (uni && g0 >= 0) {
#pragma unroll
            for (int off = 32; off > 0; off >>= 1) {
                o0 += __shfl_down(o0, off);
                o1 += __shfl_down(o1, off);
                o2 += __shfl_down(o2, off);
                o3 += __shfl_down(o3, off);
            }
            if (lane == 0) {
                unsafeAtomicAdd(&gsum[(size_t)g0 * 4 + 0], o0);
                unsafeAtomicAdd(&gsum[(size_t)g0 * 4 + 1], o1);
                unsafeAtomicAdd(&gsum[(size_t)g0 * 4 + 2], o2);
                unsafeAtomicAdd(&gsum[(size_t)g0 * 4 + 3], o3);
                unsafeAtomicAdd(&gcnt[g0], 64.0f);
            }
        } else if (valid) {
            unsafeAtomicAdd(&gsum[(size_t)g * 4 + 0], o0);
            unsafeAtomicAdd(&gsum[(size_t)g * 4 + 1], o1);
            unsafeAtomicAdd(&gsum[(size_t)g * 4 + 2], o2);
            unsafeAtomicAdd(&gsum[(size_t)g * 4 + 3], o3);
            unsafeAtomicAdd(&gcnt[g], 1.0f);
        }
    }
}

__global__ void pool_softmax_kernel(const float* __restrict__ gsum,
                                    const float* __restrict__ gcnt,
                                    float* __restrict__ out) {
    int g = blockIdx.x * blockDim.x + threadIdx.x;
    if (g >= NUM_GRAPHS) return;
    float c = fmaxf(gcnt[g], 1.0f);
    float p0 = gsum[g * 4 + 0] / c;
    float p1 = gsum[g * 4 + 1] / c;
    float p2 = gsum[g * 4 + 2] / c;
    float p3 = gsum[g * 4 + 3] / c;
    float m = fmaxf(fmaxf(p0, p1), fmaxf(p2, p3));
    float s = expf(p0 - m) + expf(p1 - m) + expf(p2 - m) + expf(p3 - m);
    float lse = m + logf(s);
    out[g * 4 + 0] = p0 - lse;
    out[g * 4 + 1] = p1 - lse;
    out[g * 4 + 2] = p2 - lse;
    out[g * 4 + 3] = p3 - lse;
}

// ---------------------------------------------------------------------------
// Naive fallback (ws too small).
// ---------------------------------------------------------------------------
__global__ void edge_scatter_kernel(const float4* __restrict__ x,
                                    const int* __restrict__ src,
                                    const int* __restrict__ dst,
                                    float* __restrict__ agg,
                                    int E) {
    int t = blockIdx.x * blockDim.x + threadIdx.x;
    int e = t * 4;
    if (e + 3 < E) {
        int4 s = *(const int4*)(src + e);
        int4 d = *(const int4*)(dst + e);
        float4 xv;
        xv = x[s.x];
        unsafeAtomicAdd(&agg[(size_t)d.x * 4 + 0], xv.x);
        unsafeAtomicAdd(&agg[(size_t)d.x * 4 + 1], xv.y);
        unsafeAtomicAdd(&agg[(size_t)d.x * 4 + 2], xv.z);
        unsafeAtomicAdd(&agg[(size_t)d.x * 4 + 3], xv.w);
        xv = x[s.y];
        unsafeAtomicAdd(&agg[(size_t)d.y * 4 + 0], xv.x);
        unsafeAtomicAdd(&agg[(size_t)d.y * 4 + 1], xv.y);
        unsafeAtomicAdd(&agg[(size_t)d.y * 4 + 2], xv.z);
        unsafeAtomicAdd(&agg[(size_t)d.y * 4 + 3], xv.w);
        xv = x[s.z];
        unsafeAtomicAdd(&agg[(size_t)d.z * 4 + 0], xv.x);
        unsafeAtomicAdd(&agg[(size_t)d.z * 4 + 1], xv.y);
        unsafeAtomicAdd(&agg[(size_t)d.z * 4 + 2], xv.z);
        unsafeAtomicAdd(&agg[(size_t)d.z * 4 + 3], xv.w);
        xv = x[s.w];
        unsafeAtomicAdd(&agg[(size_t)d.w * 4 + 0], xv.x);
        unsafeAtomicAdd(&agg[(size_t)d.w * 4 + 1], xv.y);
        unsafeAtomicAdd(&agg[(size_t)d.w * 4 + 2], xv.z);
        unsafeAtomicAdd(&agg[(size_t)d.w * 4 + 3], xv.w);
    } else {
        for (int i = e; i < E; ++i) {
            int sv = src[i], dv = dst[i];
            float4 xv = x[sv];
            unsafeAtomicAdd(&agg[(size_t)dv * 4 + 0], xv.x);
            unsafeAtomicAdd(&agg[(size_t)dv * 4 + 1], xv.y);
            unsafeAtomicAdd(&agg[(size_t)dv * 4 + 2], xv.z);
            unsafeAtomicAdd(&agg[(size_t)dv * 4 + 3], xv.w);
        }
    }
}

__global__ void node_mlp_pool_kernel(const float4* __restrict__ x,
                                     const float4* __restrict__ agg,
                                     const int* __restrict__ batch,
                                     const float* __restrict__ eps_p,
                                     const float* __restrict__ W1,
                                     const float* __restrict__ b1,
                                     const float* __restrict__ W2,
                                     const float* __restrict__ b2,
                                     float* __restrict__ gsum,
                                     float* __restrict__ gcnt,
                                     int N) {
    int i = blockIdx.x * blockDim.x + threadIdx.x;
    bool valid = i < N;
    float o0 = 0.f, o1 = 0.f, o2 = 0.f, o3 = 0.f;
    int g = -1;
    if (valid) {
        float eps = eps_p[0];
        float4 xv = x[i];
        float4 av = agg[i];
        float h0 = (1.0f + eps) * xv.x + av.x;
        float h1 = (1.0f + eps) * xv.y + av.y;
        float h2 = (1.0f + eps) * xv.z + av.z;
        float h3 = (1.0f + eps) * xv.w + av.w;
        float tmp[16];
#pragma unroll
        for (int j = 0; j < 16; ++j) {
            float v = b1[j] + h0 * W1[j] + h1 * W1[16 + j] + h2 * W1[32 + j] + h3 * W1[48 + j];
            tmp[j] = v > 0.0f ? v : 0.0f;
        }
        float o[4];
#pragma unroll
        for (int j = 0; j < 4; ++j) {
            float v = b2[j];
#pragma unroll
            for (int k = 0; k < 16; ++k) v += tmp[k] * W2[k * 4 + j];
            o[j] = v > 0.0f ? v : 0.0f;
        }
        o0 = o[0]; o1 = o[1]; o2 = o[2]; o3 = o[3];
        g = batch[i];
    }
    int g0 = __shfl(g, 0);
    bool uni = __all(g == g0);
    if (uni && g0 >= 0) {
#pragma unroll
        for (int off = 32; off > 0; off >>= 1) {
            o0 += __shfl_down(o0, off);
            o1 += __shfl_down(o1, off);
            o2 += __shfl_down(o2, off);
            o3 += __shfl_down(o3, off);
        }
        if ((threadIdx.x & 63) == 0) {
            unsafeAtomicAdd(&gsum[(size_t)g0 * 4 + 0], o0);
            unsafeAtomicAdd(&gsum[(size_t)g0 * 4 + 1], o1);
            unsafeAtomicAdd(&gsum[(size_t)g0 * 4 + 2], o2);
            unsafeAtomicAdd(&gsum[(size_t)g0 * 4 + 3], o3);
            unsafeAtomicAdd(&gcnt[g0], 64.0f);
        }
    } else if (valid) {
        unsafeAtomicAdd(&gsum[(size_t)g * 4 + 0], o0);
        unsafeAtomicAdd(&gsum[(size_t)g * 4 + 1], o1);
        unsafeAtomicAdd(&gsum[(size_t)g * 4 + 2], o2);
        unsafeAtomicAdd(&gsum[(size_t)g * 4 + 3], o3);
        unsafeAtomicAdd(&gcnt[g], 1.0f);
    }
}

extern "C" void kernel_launch(void* const* d_in, const int* in_sizes, int n_in,
                              void* d_out, int out_size, void* d_ws, size_t ws_size,
                              hipStream_t stream) {
    const float* x     = (const float*)d_in[0];
    const int*   ei    = (const int*)d_in[1];
    const int*   batch = (const int*)d_in[2];
    const float* eps   = (const float*)d_in[3];
    const float* W1    = (const float*)d_in[4];
    const float* b1    = (const float*)d_in[5];
    const float* W2    = (const float*)d_in[6];
    const float* b2    = (const float*)d_in[7];

    const int N = in_sizes[0] / 4;
    const int E = in_sizes[1] / 2;
    const int* src = ei;
    const int* dst = ei + (size_t)E;

    const int nb = (N + BIN_SIZE - 1) >> BIN_BITS;   // 489 for N=500K
    const int epb = (E + nb - 1) / nb;
    int cap = epb + epb / 8 + 1024;                  // ~28 sigma headroom
    cap = (cap + 3) & ~3;

    // ws layout: x16 [2N] | packed [nb*cap] | cursor [512*CURS] | gsum | gcnt
    size_t x16_elems = ((size_t)2 * N + 3) & ~(size_t)3;
    size_t packed_elems = ((size_t)nb * cap + 3) & ~(size_t)3;
    size_t need = (x16_elems + packed_elems + 512 * CURS + NUM_GRAPHS * 5) * sizeof(float);

    int nblocks_e = (E + EB - 1) / EB;
    bool prep_ok = (size_t)nblocks_e * STH >= (size_t)N;

    if (nb <= 512 && N < (1 << 19) && need <= ws_size && prep_ok) {
        uint2* x16    = (uint2*)d_ws;
        int*   packed = (int*)d_ws + x16_elems;
        int*   cursor = packed + packed_elems;
        float* gsum   = (float*)(cursor + 512 * CURS);
        float* gcnt   = gsum + (size_t)NUM_GRAPHS * 4;

        // ---- try the fused cooperative path ----
        static int coop_state = 0;   // 0 unknown, 1 works, -1 unavailable
        if (coop_state >= 0) {
            int devId = 0;
            (void)hipGetDevice(&devId);
            hipDeviceProp_t prop;
            (void)hipGetDeviceProperties(&prop, devId);
            int maxb = 0;
            (void)hipOccupancyMaxActiveBlocksPerMultiprocessor(&maxb, fused_gin, ACCTH, 0);
            size_t cores = (size_t)maxb * (size_t)prop.multiProcessorCount;
            if (prop.cooperativeLaunch && cores >= 1) {
                int grid_n = (int)(cores < (size_t)512 ? cores : (size_t)512);
                const float4* xf4 = (const float4*)x;
                float* outp = (float*)d_out;
                int Nv = N, Ev = E, capv = cap, nbv = nb;
                void* args[] = { (void*)&xf4, (void*)&x16, (void*)&src, (void*)&dst,
                                 (void*)&packed, (void*)&cursor, (void*)&batch,
                                 (void*)&eps, (void*)&W1, (void*)&b1, (void*)&W2,
                                 (void*)&b2, (void*)&gsum, (void*)&gcnt,
                                 (void*)&outp, (void*)&Nv, (void*)&Ev,
                                 (void*)&capv, (void*)&nbv };
                hipError_t err = hipLaunchCooperativeKernel(
                    fused_gin, dim3(grid_n), dim3(ACCTH), args, 0, stream);
                if (err == hipSuccess) { coop_state = 1; return; }
                coop_state = -1;   // not enqueued on failure; fall through
            } else {
                coop_state = -1;
            }
        }

        // ---- r8-proven 3-dispatch fallback ----
        (void)hipMemsetAsync(cursor, 0,
                             (512 * CURS + NUM_GRAPHS * 5) * sizeof(int), stream);
        bin_scatter<<<nblocks_e, STH, 0, stream>>>(
            (const float4*)x, x16, src, dst, packed, cursor, N, E, cap, nb);
        bin_accum_mlp_pool<<<nb, ACCTH, 0, stream>>>(
            (const float4*)x, (const uint2*)x16, packed, cursor, batch, eps,
            W1, b1, W2, b2, gsum, gcnt, N, cap);
        pool_softmax_kernel<<<(NUM_GRAPHS + 255) / 256, 256, 0, stream>>>(
            gsum, gcnt, (float*)d_out);
    } else {
        float* agg  = (float*)d_ws;
        float* gsum = agg + (size_t)N * 4;
        float* gcnt = gsum + (size_t)NUM_GRAPHS * 4;
        size_t zero_bytes = ((size_t)N * 4 + NUM_GRAPHS * 5) * sizeof(float);
        (void)hipMemsetAsync(d_ws, 0, zero_bytes, stream);

        int e4 = (E + 3) / 4;
        edge_scatter_kernel<<<(e4 + 255) / 256, 256, 0, stream>>>(
            (const float4*)x, src, dst, agg, E);
        node_mlp_pool_kernel<<<(N + 255) / 256, 256, 0, stream>>>(
            (const float4*)x, (const float4*)agg, batch, eps, W1, b1, W2, b2,
            gsum, gcnt, N);
        pool_softmax_kernel<<<(NUM_GRAPHS + 255) / 256, 256, 0, stream>>>(
            gsum, gcnt, (float*)d_out);
    }
}

// Round 11
// 541.614 us; speedup vs baseline: 1.4261x; 1.4261x over previous
//
#include <hip/hip_runtime.h>

#define NUM_GRAPHS 1024
#define BIN_BITS 9
#define BIN_SIZE (1 << BIN_BITS)      // 512 nodes per bin
#define NBINS 1024                    // max bins (N < 2^19 -> nb <= 1024)
#define EB 4096                       // edges per binning block
#define STH 512                       // scatter threads (8 waves)
#define EPT 8                         // edges per thread in scatter (EB/STH)
#define SWAVES 8                      // scatter waves per block
#define CURS 16                       // cursor stride in ints (64 B = 1 line)
#define ACCTH 256                     // accum threads (4 waves)
#define ACCW 4                        // waves per accum block

typedef int v4i __attribute__((ext_vector_type(4)));  // native vec for nt-load

__device__ inline unsigned bf16_rn(float f) {
    unsigned u = __float_as_uint(f);
    return (u + 0x7FFFu + ((u >> 16) & 1u)) >> 16;
}

// ---------------------------------------------------------------------------
// bin_scatter v10 = v9 with 1024 bins (BIN_BITS=9) at ZERO extra LDS:
// the combine phase writes per-wave bases IN-PLACE into hist (read c[w]
// first, then overwrite) — no separate wbase array, LDS stays 32 KB,
// 4 blocks/CU (32 waves). Proven pieces kept: prep folded as phase 0
// (bf16x4 table, 4 MB = L2-resident; r6: f32 at 8 MB misses L2, 523 MB
// HBM); zero per-edge atomics (ballot-match ranking, per-wave hist);
// plain stores through L2 (r4: NEVER nt-store scattered sub-line data).
// packed = (dst_local << 19) | src,  dst_local < 512.
// ---------------------------------------------------------------------------
__global__ void __launch_bounds__(STH) bin_scatter(const float4* __restrict__ x,
                                                   uint2* __restrict__ x16,
                                                   const int* __restrict__ src,
                                                   const int* __restrict__ dst,
                                                   int* __restrict__ packed,
                                                   int* __restrict__ cursor,
                                                   int N, int E, int cap, int nb) {
    __shared__ int hist[SWAVES][NBINS];   // 32 KB; doubles as wbase after combine

    const int t = threadIdx.x;
    const int lane = t & 63;
    const int wave = t >> 6;
    const int b0 = blockIdx.x * EB;
    const int myBase = b0 + t * EPT;

    // ---- phase 0: prep (x -> bf16x4 table) ----
    {
        int nd = blockIdx.x * STH + t;
        if (nd < N) {
            float4 v = x[nd];
            uint2 r;
            r.x = bf16_rn(v.x) | (bf16_rn(v.y) << 16);
            r.y = bf16_rn(v.z) | (bf16_rn(v.w) << 16);
            x16[nd] = r;
        }
    }

    for (int j = t; j < SWAVES * NBINS; j += STH) (&hist[0][0])[j] = 0;
    __syncthreads();

    // ---- load 8 edges per thread (two int4 each of src/dst) ----
    int dbuf[EPT], sbuf[EPT];
    const bool full = (myBase + EPT <= E);
    if (full) {
        *(int4*)(dbuf)     = *(const int4*)(dst + myBase);
        *(int4*)(dbuf + 4) = *(const int4*)(dst + myBase + 4);
        *(int4*)(sbuf)     = *(const int4*)(src + myBase);
        *(int4*)(sbuf + 4) = *(const int4*)(src + myBase + 4);
    } else {
#pragma unroll
        for (int i = 0; i < EPT; ++i) {
            int e = myBase + i;
            bool ok = e < E;
            dbuf[i] = ok ? dst[e] : 0;
            sbuf[i] = ok ? src[e] : 0;
        }
    }

    // ---- pass A: ballot-match ranking, plain LDS RMW (no atomics) ----
    int pv[EPT];                   // packed edge values
    int bnlp[EPT];                 // (bn << 16) | lp, or -1 if invalid
#pragma unroll
    for (int k = 0; k < EPT; ++k) {
        int e = myBase + k;
        bool ok = full || (e < E);
        int d = dbuf[k];
        int bn = ((unsigned)d) >> BIN_BITS;            // < 1024
        pv[k] = ((d & (BIN_SIZE - 1)) << 19) | sbuf[k];
        unsigned long long m = __ballot(ok);
#pragma unroll
        for (int bb = 0; bb < 10; ++bb) {
            unsigned long long bm = __ballot((bn >> bb) & 1);
            m &= ((bn >> bb) & 1) ? bm : ~bm;
        }
        int rank = (int)__popcll(m & ((1ull << lane) - 1ull));
        int cnt  = (int)__popcll(m);
        int leader = __ffsll((unsigned long long)m) - 1;
        int old = hist[wave][bn];                      // group lanes: same addr
        if (ok && lane == leader) hist[wave][bn] = old + cnt;
        bnlp[k] = ok ? ((bn << 16) | (old + rank)) : -1;
    }
    __syncthreads();

    // ---- combine: per-bin cross-wave prefix + single cursor reserve;
    //      bases written IN-PLACE into hist (read-before-write per j) ----
    for (int j = t; j < NBINS; j += STH) {
        int c[SWAVES];
        int total = 0;
#pragma unroll
        for (int w = 0; w < SWAVES; ++w) { c[w] = hist[w][j]; total += c[w]; }
        int base = j * cap;                 // cursors are relative counts
        if (j < nb && total > 0) base += atomicAdd(&cursor[j * CURS], total);
        int acc = base;
#pragma unroll
        for (int w = 0; w < SWAVES; ++w) { hist[w][j] = acc; acc += c[w]; }
    }
    __syncthreads();

    // ---- pass B: direct scattered stores THROUGH L2 (plain, not nt) ----
    if (full) {
#pragma unroll
        for (int k = 0; k < EPT; ++k) {
            int bn = ((unsigned)bnlp[k]) >> 16;
            int lp = bnlp[k] & 0xFFFF;
            int pos = hist[wave][bn] + lp;
            if (pos < (bn + 1) * cap)          // overflow guard (~12 sigma)
                packed[pos] = pv[k];
        }
    } else {
#pragma unroll
        for (int k = 0; k < EPT; ++k) {
            if (bnlp[k] >= 0) {
                int bn = ((unsigned)bnlp[k]) >> 16;
                int lp = bnlp[k] & 0xFFFF;
                int pos = hist[wave][bn] + lp;
                if (pos < (bn + 1) * cap)
                    packed[pos] = pv[k];
            }
        }
    }
}

// ---------------------------------------------------------------------------
// Accum v12 = v7 machinery at HALF bin size: planes [4][512][4] f32 = 32 KB
// -> 5 blocks/CU by LDS; grid 977 blocks (~3.8/CU) -> ~15 waves/CU, 2x r8's
// 8 (r8 diagnosis: latency-bound on the divergent L2 gather; only occupancy
// hides it — r9's split+merge failed on merge traffic; this shrinks bins at
// the SOURCE so each bin stays single-block, merge-free).
// Zero atomics: 9-ballot match + rank-ordered multipass RMW (measured best
// across 5 variants). r10: fixed ~125 us harness overhead is untouchable;
// kernel interiors are the only budget.
// ---------------------------------------------------------------------------
#define LOADR(B, PE, VM) do {                                              \
    int _i = (B) + lane * 4;                                               \
    if (_i + 3 < s1) {                                                     \
        v4i _p4 = __builtin_nontemporal_load((const v4i*)(packed + _i));   \
        PE[0] = _p4.x; PE[1] = _p4.y; PE[2] = _p4.z; PE[3] = _p4.w;        \
        VM = 0xF;                                                          \
    } else {                                                               \
        VM = 0;                                                            \
        PE[0] = (_i + 0 < s1) ? (VM |= 1, packed[_i + 0]) : 0;             \
        PE[1] = (_i + 1 < s1) ? (VM |= 2, packed[_i + 1]) : 0;             \
        PE[2] = (_i + 2 < s1) ? (VM |= 4, packed[_i + 2]) : 0;             \
        PE[3] = (_i + 3 < s1) ? (VM |= 8, packed[_i + 3]) : 0;             \
    }                                                                      \
} while (0)

#define GATHR(PE, G) do {                                                  \
    G[0] = x16[PE[0] & 0x7FFFF];                                           \
    G[1] = x16[PE[1] & 0x7FFFF];                                           \
    G[2] = x16[PE[2] & 0x7FFFF];                                           \
    G[3] = x16[PE[3] & 0x7FFFF];                                           \
} while (0)

#define PROCR(PE, G, VM) do {                                              \
    _Pragma("unroll")                                                      \
    for (int k = 0; k < 4; ++k) {                                          \
        int p = PE[k];                                                     \
        int dl = (((unsigned)p) >> 19) & (BIN_SIZE - 1);                   \
        unsigned long long m = ~0ull;                                      \
        _Pragma("unroll")                                                  \
        for (int bb = 0; bb < BIN_BITS; ++bb) {                            \
            unsigned long long bm = __ballot((dl >> bb) & 1);              \
            m &= ((dl >> bb) & 1) ? bm : ~bm;                              \
        }                                                                  \
        int rank = (int)__popcll(m & ((1ull << lane) - 1ull));             \
        float sc = ((VM >> k) & 1) ? 1.0f : 0.0f;                          \
        float v0 = __uint_as_float(G[k].x << 16) * sc;                     \
        float v1 = __uint_as_float(G[k].x & 0xFFFF0000u) * sc;             \
        float v2 = __uint_as_float(G[k].y << 16) * sc;                     \
        float v3 = __uint_as_float(G[k].y & 0xFFFF0000u) * sc;             \
        float4* pp = (float4*)&planes[wave][dl][0];                        \
        for (int pass = 0; __any(rank >= pass); ++pass) {                  \
            if (rank == pass) {                                            \
                float4 a = *pp;                                            \
                a.x += v0; a.y += v1; a.z += v2; a.w += v3;                \
                *pp = a;                                                   \
            }                                                              \
        }                                                                  \
    }                                                                      \
} while (0)

__global__ void __launch_bounds__(ACCTH) bin_accum_mlp_pool(
        const float4* __restrict__ x,
        const uint2* __restrict__ x16,
        const int* __restrict__ packed,
        const int* __restrict__ cursor,
        const int* __restrict__ batch,
        const float* __restrict__ eps_p,
        const float* __restrict__ W1, const float* __restrict__ b1,
        const float* __restrict__ W2, const float* __restrict__ b2,
        float* __restrict__ gsum, float* __restrict__ gcnt,
        int N, int cap) {
    __shared__ float planes[ACCW][BIN_SIZE][4];   // 32 KB, per-wave private

    const int bin = blockIdx.x;
    const int t = threadIdx.x;
    const int lane = t & 63;
    const int wave = t >> 6;

    // zero planes: 2048 float4s / 256 threads = 8 each
    {
        float4 z; z.x = 0.f; z.y = 0.f; z.z = 0.f; z.w = 0.f;
        float4* pz = (float4*)&planes[0][0][0];
#pragma unroll
        for (int i = 0; i < 8; ++i) pz[t + i * ACCTH] = z;
    }
    __syncthreads();

    const int startb = bin * cap;
    int cnt = cursor[bin * CURS];                 // relative count
    if (cnt > cap) cnt = cap;
    if (cnt < 0) cnt = 0;
    const int endb = startb + cnt;
    int seg = ((cnt + ACCW - 1) / ACCW + 3) & ~3;
    int s0 = startb + wave * seg;
    int s1 = s0 + seg; if (s1 > endb) s1 = endb;

    for (int b = s0; b < s1; b += 256) {
        int pe[4]; int vm; uint2 g[4];
        LOADR(b, pe, vm);
        GATHR(pe, g);
        PROCR(pe, g, vm);
    }
    __syncthreads();

    // ---- reduce 4 planes + MLP + pool; 2 node-batches of 256 ----
    const float eps = eps_p[0];
    for (int hb = 0; hb < 2; ++hb) {
        int node = t + hb * ACCTH;             // 0..511
        float4 a = *(const float4*)&planes[0][node][0];
#pragma unroll
        for (int w = 1; w < ACCW; ++w) {
            float4 bq = *(const float4*)&planes[w][node][0];
            a.x += bq.x; a.y += bq.y; a.z += bq.z; a.w += bq.w;
        }

        int n = bin * BIN_SIZE + node;         // one node per thread
        bool valid = n < N;
        float o0 = 0.f, o1 = 0.f, o2 = 0.f, o3 = 0.f;
        int g = -1;
        if (valid) {
            float4 xv = x[n];
            float h0 = (1.0f + eps) * xv.x + a.x;
            float h1 = (1.0f + eps) * xv.y + a.y;
            float h2 = (1.0f + eps) * xv.z + a.z;
            float h3 = (1.0f + eps) * xv.w + a.w;

            float tmp[16];
#pragma unroll
            for (int j = 0; j < 16; ++j) {
                float v = b1[j] + h0 * W1[j] + h1 * W1[16 + j] + h2 * W1[32 + j] + h3 * W1[48 + j];
                tmp[j] = v > 0.0f ? v : 0.0f;
            }
            float o[4];
#pragma unroll
            for (int j = 0; j < 4; ++j) {
                float v = b2[j];
#pragma unroll
                for (int k = 0; k < 16; ++k) v += tmp[k] * W2[k * 4 + j];
                o[j] = v > 0.0f ? v : 0.0f;
            }
            o0 = o[0]; o1 = o[1]; o2 = o[2]; o3 = o[3];
            g = batch[n];
        }

        // batch is sorted -> waves almost always graph-uniform
        int g0 = __shfl(g, 0);
        bool uni = __all(g == g0);
        if (uni && g0 >= 0) {
#pragma unroll
            for (int off = 32; off > 0; off >>= 1) {
                o0 += __shfl_down(o0, off);
                o1 += __shfl_down(o1, off);
                o2 += __shfl_down(o2, off);
                o3 += __shfl_down(o3, off);
            }
            if (lane == 0) {
                unsafeAtomicAdd(&gsum[(size_t)g0 * 4 + 0], o0);
                unsafeAtomicAdd(&gsum[(size_t)g0 * 4 + 1], o1);
                unsafeAtomicAdd(&gsum[(size_t)g0 * 4 + 2], o2);
                unsafeAtomicAdd(&gsum[(size_t)g0 * 4 + 3], o3);
                unsafeAtomicAdd(&gcnt[g0], 64.0f);
            }
        } else if (valid) {
            unsafeAtomicAdd(&gsum[(size_t)g * 4 + 0], o0);
            unsafeAtomicAdd(&gsum[(size_t)g * 4 + 1], o1);
            unsafeAtomicAdd(&gsum[(size_t)g * 4 + 2], o2);
            unsafeAtomicAdd(&gsum[(size_t)g * 4 + 3], o3);
            unsafeAtomicAdd(&gcnt[g], 1.0f);
        }
    }
}

// ---------------------------------------------------------------------------
// pooled = sums / max(cnt,1); out = log_softmax per graph.
// ---------------------------------------------------------------------------
__global__ void pool_softmax_kernel(const float* __restrict__ gsum,
                                    const float* __restrict__ gcnt,
                                    float* __restrict__ out) {
    int g = blockIdx.x * blockDim.x + threadIdx.x;
    if (g >= NUM_GRAPHS) return;
    float c = fmaxf(gcnt[g], 1.0f);
    float p0 = gsum[g * 4 + 0] / c;
    float p1 = gsum[g * 4 + 1] / c;
    float p2 = gsum[g * 4 + 2] / c;
    float p3 = gsum[g * 4 + 3] / c;
    float m = fmaxf(fmaxf(p0, p1), fmaxf(p2, p3));
    float s = expf(p0 - m) + expf(p1 - m) + expf(p2 - m) + expf(p3 - m);
    float lse = m + logf(s);
    out[g * 4 + 0] = p0 - lse;
    out[g * 4 + 1] = p1 - lse;
    out[g * 4 + 2] = p2 - lse;
    out[g * 4 + 3] = p3 - lse;
}

// ---------------------------------------------------------------------------
// Fallback kernels (ws too small): direct atomic scatter + separate MLP/pool.
// ---------------------------------------------------------------------------
__global__ void edge_scatter_kernel(const float4* __restrict__ x,
                                    const int* __restrict__ src,
                                    const int* __restrict__ dst,
                                    float* __restrict__ agg,
                                    int E) {
    int t = blockIdx.x * blockDim.x + threadIdx.x;
    int e = t * 4;
    if (e + 3 < E) {
        int4 s = *(const int4*)(src + e);
        int4 d = *(const int4*)(dst + e);
        float4 xv;
        xv = x[s.x];
        unsafeAtomicAdd(&agg[(size_t)d.x * 4 + 0], xv.x);
        unsafeAtomicAdd(&agg[(size_t)d.x * 4 + 1], xv.y);
        unsafeAtomicAdd(&agg[(size_t)d.x * 4 + 2], xv.z);
        unsafeAtomicAdd(&agg[(size_t)d.x * 4 + 3], xv.w);
        xv = x[s.y];
        unsafeAtomicAdd(&agg[(size_t)d.y * 4 + 0], xv.x);
        unsafeAtomicAdd(&agg[(size_t)d.y * 4 + 1], xv.y);
        unsafeAtomicAdd(&agg[(size_t)d.y * 4 + 2], xv.z);
        unsafeAtomicAdd(&agg[(size_t)d.y * 4 + 3], xv.w);
        xv = x[s.z];
        unsafeAtomicAdd(&agg[(size_t)d.z * 4 + 0], xv.x);
        unsafeAtomicAdd(&agg[(size_t)d.z * 4 + 1], xv.y);
        unsafeAtomicAdd(&agg[(size_t)d.z * 4 + 2], xv.z);
        unsafeAtomicAdd(&agg[(size_t)d.z * 4 + 3], xv.w);
        xv = x[s.w];
        unsafeAtomicAdd(&agg[(size_t)d.w * 4 + 0], xv.x);
        unsafeAtomicAdd(&agg[(size_t)d.w * 4 + 1], xv.y);
        unsafeAtomicAdd(&agg[(size_t)d.w * 4 + 2], xv.z);
        unsafeAtomicAdd(&agg[(size_t)d.w * 4 + 3], xv.w);
    } else {
        for (int i = e; i < E; ++i) {
            int sv = src[i], dv = dst[i];
            float4 xv = x[sv];
            unsafeAtomicAdd(&agg[(size_t)dv * 4 + 0], xv.x);
            unsafeAtomicAdd(&agg[(size_t)dv * 4 + 1], xv.y);
            unsafeAtomicAdd(&agg[(size_t)dv * 4 + 2], xv.z);
            unsafeAtomicAdd(&agg[(size_t)dv * 4 + 3], xv.w);
        }
    }
}

__global__ void node_mlp_pool_kernel(const float4* __restrict__ x,
                                     const float4* __restrict__ agg,
                                     const int* __restrict__ batch,
                                     const float* __restrict__ eps_p,
                                     const float* __restrict__ W1,
                                     const float* __restrict__ b1,
                                     const float* __restrict__ W2,
                                     const float* __restrict__ b2,
                                     float* __restrict__ gsum,
                                     float* __restrict__ gcnt,
                                     int N) {
    int i = blockIdx.x * blockDim.x + threadIdx.x;
    bool valid = i < N;
    float o0 = 0.f, o1 = 0.f, o2 = 0.f, o3 = 0.f;
    int g = -1;
    if (valid) {
        float eps = eps_p[0];
        float4 xv = x[i];
        float4 av = agg[i];
        float h0 = (1.0f + eps) * xv.x + av.x;
        float h1 = (1.0f + eps) * xv.y + av.y;
        float h2 = (1.0f + eps) * xv.z + av.z;
        float h3 = (1.0f + eps) * xv.w + av.w;
        float tmp[16];
#pragma unroll
        for (int j = 0; j < 16; ++j) {
            float v = b1[j] + h0 * W1[j] + h1 * W1[16 + j] + h2 * W1[32 + j] + h3 * W1[48 + j];
            tmp[j] = v > 0.0f ? v : 0.0f;
        }
        float o[4];
#pragma unroll
        for (int j = 0; j < 4; ++j) {
            float v = b2[j];
#pragma unroll
            for (int k = 0; k < 16; ++k) v += tmp[k] * W2[k * 4 + j];
            o[j] = v > 0.0f ? v : 0.0f;
        }
        o0 = o[0]; o1 = o[1]; o2 = o[2]; o3 = o[3];
        g = batch[i];
    }
    int g0 = __shfl(g, 0);
    bool uni = __all(g == g0);
    if (uni && g0 >= 0) {
#pragma unroll
        for (int off = 32; off > 0; off >>= 1) {
            o0 += __shfl_down(o0, off);
            o1 += __shfl_down(o1, off);
            o2 += __shfl_down(o2, off);
            o3 += __shfl_down(o3, off);
        }
        if ((threadIdx.x & 63) == 0) {
            unsafeAtomicAdd(&gsum[(size_t)g0 * 4 + 0], o0);
            unsafeAtomicAdd(&gsum[(size_t)g0 * 4 + 1], o1);
            unsafeAtomicAdd(&gsum[(size_t)g0 * 4 + 2], o2);
            unsafeAtomicAdd(&gsum[(size_t)g0 * 4 + 3], o3);
            unsafeAtomicAdd(&gcnt[g0], 64.0f);
        }
    } else if (valid) {
        unsafeAtomicAdd(&gsum[(size_t)g * 4 + 0], o0);
        unsafeAtomicAdd(&gsum[(size_t)g * 4 + 1], o1);
        unsafeAtomicAdd(&gsum[(size_t)g * 4 + 2], o2);
        unsafeAtomicAdd(&gsum[(size_t)g * 4 + 3], o3);
        unsafeAtomicAdd(&gcnt[g], 1.0f);
    }
}

extern "C" void kernel_launch(void* const* d_in, const int* in_sizes, int n_in,
                              void* d_out, int out_size, void* d_ws, size_t ws_size,
                              hipStream_t stream) {
    const float* x     = (const float*)d_in[0];
    const int*   ei    = (const int*)d_in[1];
    const int*   batch = (const int*)d_in[2];
    const float* eps   = (const float*)d_in[3];
    const float* W1    = (const float*)d_in[4];
    const float* b1    = (const float*)d_in[5];
    const float* W2    = (const float*)d_in[6];
    const float* b2    = (const float*)d_in[7];

    const int N = in_sizes[0] / 4;
    const int E = in_sizes[1] / 2;
    const int* src = ei;
    const int* dst = ei + (size_t)E;

    const int nb = (N + BIN_SIZE - 1) >> BIN_BITS;   // 977 for N=500K
    const int epb = (E + nb - 1) / nb;               // ~16.4K
    int cap = epb + epb / 16 + 512;                  // ~12 sigma headroom
    cap = (cap + 3) & ~3;                            // 16B-align chunk bases

    // Fast-path ws layout: x16 [2N] | packed [nb*cap] | cursor [NBINS*CURS] |
    //                      gsum [G*4] | gcnt [G]      (4 B units)
    size_t x16_elems = ((size_t)2 * N + 3) & ~(size_t)3;
    size_t packed_elems = ((size_t)nb * cap + 3) & ~(size_t)3;
    size_t need = (x16_elems + packed_elems + NBINS * CURS + NUM_GRAPHS * 5) * sizeof(float);

    // prep coverage check: scatter grid must span N nodes in phase 0
    int nblocks_e = (E + EB - 1) / EB;
    bool prep_ok = (size_t)nblocks_e * STH >= (size_t)N;

    if (nb <= NBINS && N < (1 << 19) && need <= ws_size && prep_ok) {
        uint2* x16    = (uint2*)d_ws;
        int*   packed = (int*)d_ws + x16_elems;
        int*   cursor = packed + packed_elems;
        float* gsum   = (float*)(cursor + NBINS * CURS);
        float* gcnt   = gsum + (size_t)NUM_GRAPHS * 4;

        // cursor + gsum + gcnt are contiguous: one async memset.
        (void)hipMemsetAsync(cursor, 0,
                             (NBINS * CURS + NUM_GRAPHS * 5) * sizeof(int), stream);

        bin_scatter<<<nblocks_e, STH, 0, stream>>>(
            (const float4*)x, x16, src, dst, packed, cursor, N, E, cap, nb);

        bin_accum_mlp_pool<<<nb, ACCTH, 0, stream>>>(
            (const float4*)x, (const uint2*)x16, packed, cursor, batch, eps,
            W1, b1, W2, b2, gsum, gcnt, N, cap);

        pool_softmax_kernel<<<(NUM_GRAPHS + 255) / 256, 256, 0, stream>>>(
            gsum, gcnt, (float*)d_out);
    } else {
        float* agg  = (float*)d_ws;
        float* gsum = agg + (size_t)N * 4;
        float* gcnt = gsum + (size_t)NUM_GRAPHS * 4;
        size_t zero_bytes = ((size_t)N * 4 + NUM_GRAPHS * 5) * sizeof(float);
        (void)hipMemsetAsync(d_ws, 0, zero_bytes, stream);

        int e4 = (E + 3) / 4;
        edge_scatter_kernel<<<(e4 + 255) / 256, 256, 0, stream>>>(
            (const float4*)x, src, dst, agg, E);

        node_mlp_pool_kernel<<<(N + 255) / 256, 256, 0, stream>>>(
            (const float4*)x, (const float4*)agg, batch, eps, W1, b1, W2, b2,
            gsum, gcnt, N);

        pool_softmax_kernel<<<(NUM_GRAPHS + 255) / 256, 256, 0, stream>>>(
            gsum, gcnt, (float*)d_out);
    }
}